// Round 9
// baseline (598.325 us; speedup 1.0000x reference)
//
#include <hip/hip_runtime.h>
#include <cstdint>
#include <cstddef>

// Problem constants (B,N,M,D fixed by the reference setup_inputs)
#define BB 8
#define NPTS 2048
#define DIM 64
#define CK 32            // Q cols staged per sub-chunk
#define HALFC 1024       // cols per block (col-split by 2)
#define NCH (HALFC / CK) // 32 sub-chunks

typedef _Float16 f16x8 __attribute__((ext_vector_type(8)));
typedef float f32x16 __attribute__((ext_vector_type(16)));

// eps schedule: DIAMETER^2 * 0.25^k down to blur^2 = 0.0025 (9 entries)
static const float EPS_H[9] = {100.0f, 25.0f, 6.25f, 1.5625f, 0.390625f,
                               0.09765625f, 0.0244140625f, 0.006103515625f,
                               0.0025f};
#define LOG2E 1.4426950408889634f
#define LN2 0.6931471805599453f

#if __has_builtin(__builtin_amdgcn_exp2f)
static __device__ __forceinline__ float fexp2(float x) {
  return __builtin_amdgcn_exp2f(x);
}
#else
static __device__ __forceinline__ float fexp2(float x) {
  float r;
  asm("v_exp_f32 %0, %1" : "=v"(r) : "v"(x));
  return r;
}
#endif

static __device__ __forceinline__ void gload_lds16(const void* g, void* l) {
  __builtin_amdgcn_global_load_lds(
      (const __attribute__((address_space(1))) void*)g,
      (__attribute__((address_space(3))) void*)l, 16, 0, 0);
}

struct FT {
  const _Float16* P;  // row-side points [B,2048,64]
  const _Float16* Q;  // reduce-side points [B,2048,64]
};
struct MT {
  const float* psq;  // |p|^2 on output rows
  const float* oldf; // averaging input (nullptr = none)
  float* out;        // potential output [B,2048]
  const float* lwn;  // log-weights for NEXT round's hq (Q-side of consumer)
  const float* q2n;  // |q|^2 for NEXT round's hq
  float* hqn;        // hq slice of the consumer task
};

// ---------------- prep kernels ----------------

__global__ __launch_bounds__(256) void norm_weights_k(
    const float* __restrict__ w, float* __restrict__ aout,
    float* __restrict__ logout, int n) {
  int b = blockIdx.x;
  const float* wb = w + (size_t)b * n;
  __shared__ float red[256];
  float s = 0.f;
  for (int i = threadIdx.x; i < n; i += 256) s += wb[i];
  red[threadIdx.x] = s;
  __syncthreads();
  for (int st = 128; st > 0; st >>= 1) {
    if (threadIdx.x < st) red[threadIdx.x] += red[threadIdx.x + st];
    __syncthreads();
  }
  float mass = red[0];
  if (mass == 0.f) mass = 1.f;
  float inv = 1.f / mass;
  for (int i = threadIdx.x; i < n; i += 256) {
    float av = wb[i] * inv;
    aout[(size_t)b * n + i] = av;
    logout[(size_t)b * n + i] = logf(av);
  }
}

// squared norm of each D=64 row + fp16 conversion: one wave per row
__global__ __launch_bounds__(256) void sqnorm_cvt_k(
    const float* __restrict__ X, float* __restrict__ sq,
    _Float16* __restrict__ Xh, int rows) {
  int row = blockIdx.x * 4 + (threadIdx.x >> 6);
  int lane = threadIdx.x & 63;
  if (row >= rows) return;
  float v = X[(size_t)row * DIM + lane];
  Xh[(size_t)row * DIM + lane] = (_Float16)v;
  float s = v * v;
  #pragma unroll
  for (int off = 32; off > 0; off >>= 1) s += __shfl_xor(s, off);
  if (lane == 0) sq[row] = s;
}

// hq init (no potential): hq[t][b][m] = lw*log2e - 0.5*q2*ie2
__global__ __launch_bounds__(256) void init_hq_k(
    const float* __restrict__ la, const float* __restrict__ lb,
    const float* __restrict__ x2, const float* __restrict__ y2,
    float* __restrict__ hq, float ie2) {
  int task = blockIdx.z;
  int idx = blockIdx.x * 256 + threadIdx.x;  // over BB*NPTS
  const float* lw = (task == 1 || task == 2) ? la : lb;
  const float* q2 = (task == 1 || task == 2) ? x2 : y2;
  hq[(size_t)task * BB * NPTS + idx] =
      fmaf(lw[idx], LOG2E, -0.5f * q2[idx] * ie2);
}

// ---------------- fused cost+softmin (1-wave self-paced, 32x32 MFMA) -------
// Partial over one col-half: (mx,sm)[task][b][row][half] with
//   v[r,m] = hq[m] + dot(P_r,Q_m)*ie2  (f16 MFMA 32x32x16, fp32 acc)
// Block = 1 wave, 32 P-rows, 1024 cols swept in 32-col LDS sub-chunks.
// Private double-buffer; counted vmcnt(5) (4 stage + 1 hq load per chunk);
// NO barriers. Rescale amortized per 2 sub-chunks.
__global__ __launch_bounds__(64, 4) void fused_softmin_k(
    FT t0, FT t1, FT t2, FT t3, const float* __restrict__ hqG,
    float* __restrict__ pmx, float* __restrict__ psm, float ie2) {
  __shared__ __align__(16) _Float16 qb[2][CK * DIM];  // 2 x 4 KB
  FT T = (blockIdx.z == 0) ? t0
       : (blockIdx.z == 1) ? t1
       : (blockIdx.z == 2) ? t2 : t3;
  const int rowg = blockIdx.x >> 1, half = blockIdx.x & 1;
  const int b = blockIdx.y, task = blockIdx.z;
  const int lane = threadIdx.x;
  const int l31 = lane & 31, hi = lane >> 5;

  const _Float16* Qb = T.Q + ((size_t)b * NPTS + half * HALFC) * DIM;
  const float* hqp = hqG + ((size_t)task * BB + b) * NPTS + half * HALFC;

  // A fragments: rows rowg*32 .. +31, K=64 as 4 K16 segments.
  // 32x32x16 A layout: row = l&31, k = (l>>5)*8 + j  (m89 pattern generalized)
  const _Float16* Pb = T.P + ((size_t)b * NPTS + rowg * 32) * DIM;
  f16x8 a[4];
  #pragma unroll
  for (int s = 0; s < 4; ++s)
    a[s] = *(const f16x8*)(Pb + (size_t)l31 * DIM + s * 16 + hi * 8);

  // B ds_read byte addresses in qb[0]: row=l31, granule g=2s+hi, XOR-swizzled
  int baddr[4];
  #pragma unroll
  for (int s = 0; s < 4; ++s)
    baddr[s] = l31 * 128 + (((2 * s + hi) ^ (l31 & 7)) << 4);
  const char* qb0 = (const char*)&qb[0][0];

  // stage: linear LDS dest (wave-uniform base, lane x 16B), inverse-swizzled
  // global source (rule #21): granule gid holds Q[m0+gid/8][kg=(gid%8)^(row&7)]
  auto stage = [&](int buf, int c) {
    int m0 = c * CK;
    #pragma unroll
    for (int r = 0; r < 4; ++r) {
      int gid = r * 64 + lane;
      int row = gid >> 3;
      int kg = (gid & 7) ^ (row & 7);
      gload_lds16(Qb + (size_t)(m0 + row) * DIM + kg * 8, &qb[buf][r * 512]);
    }
  };

  float mx[16], sm[16];
  #pragma unroll
  for (int r = 0; r < 16; ++r) { mx[r] = -3.0e38f; sm[r] = 0.f; }

  stage(0, 0);
  float hq_c = hqp[l31];  // chunk 0 (lanes 0-31 / 32-63 broadcast-pair)
  float v0[16], v1[16];

#define SUB(c_, BUF_, VOUT_, LAST_)                                          \
  {                                                                          \
    float hq_n = 0.f;                                                        \
    if (!(LAST_)) {                                                          \
      stage((BUF_) ^ 1, (c_) + 1);                                           \
      hq_n = hqp[((c_) + 1) * CK + l31];                                     \
    }                                                                        \
    if (LAST_) asm volatile("s_waitcnt vmcnt(0)" ::: "memory");              \
    else       asm volatile("s_waitcnt vmcnt(5)" ::: "memory");              \
    __builtin_amdgcn_sched_barrier(0);                                       \
    f16x8 b0 = *(const f16x8*)(qb0 + (BUF_) * 4096 + baddr[0]);              \
    f16x8 b1 = *(const f16x8*)(qb0 + (BUF_) * 4096 + baddr[1]);              \
    f16x8 b2 = *(const f16x8*)(qb0 + (BUF_) * 4096 + baddr[2]);              \
    f16x8 b3 = *(const f16x8*)(qb0 + (BUF_) * 4096 + baddr[3]);              \
    f32x16 acc = {};                                                         \
    __builtin_amdgcn_s_setprio(1);                                           \
    acc = __builtin_amdgcn_mfma_f32_32x32x16_f16(a[0], b0, acc, 0, 0, 0);    \
    acc = __builtin_amdgcn_mfma_f32_32x32x16_f16(a[1], b1, acc, 0, 0, 0);    \
    acc = __builtin_amdgcn_mfma_f32_32x32x16_f16(a[2], b2, acc, 0, 0, 0);    \
    acc = __builtin_amdgcn_mfma_f32_32x32x16_f16(a[3], b3, acc, 0, 0, 0);    \
    __builtin_amdgcn_s_setprio(0);                                           \
    _Pragma("unroll")                                                        \
    for (int r = 0; r < 16; ++r) (VOUT_)[r] = fmaf(acc[r], ie2, hq_c);       \
    hq_c = hq_n;                                                             \
  }

#define PAIR_TAIL()                                                          \
  _Pragma("unroll")                                                          \
  for (int r = 0; r < 16; ++r) {                                             \
    float cm = fmaxf(fmaxf(mx[r], v0[r]), v1[r]);                            \
    float e = fexp2(v0[r] - cm) + fexp2(v1[r] - cm);                         \
    sm[r] = fmaf(sm[r], fexp2(mx[r] - cm), e);                               \
    mx[r] = cm;                                                              \
  }

  for (int cp = 0; cp < NCH / 2 - 1; ++cp) {
    SUB(2 * cp, 0, v0, false)
    SUB(2 * cp + 1, 1, v1, false)
    PAIR_TAIL()
  }
  SUB(NCH - 2, 0, v0, false)
  SUB(NCH - 1, 1, v1, true)
  PAIR_TAIL()
#undef SUB
#undef PAIR_TAIL

  // reduce over the 32 cols (lanes l31=0..31 within each hi-half):
  // max-reduce first, then single rescale per reg, then sum-reduce.
  float fm[16];
  #pragma unroll
  for (int r = 0; r < 16; ++r) fm[r] = mx[r];
  #pragma unroll
  for (int off = 1; off < 32; off <<= 1) {
    #pragma unroll
    for (int r = 0; r < 16; ++r) fm[r] = fmaxf(fm[r], __shfl_xor(fm[r], off));
  }
  #pragma unroll
  for (int r = 0; r < 16; ++r) sm[r] *= fexp2(mx[r] - fm[r]);
  #pragma unroll
  for (int off = 1; off < 32; off <<= 1) {
    #pragma unroll
    for (int r = 0; r < 16; ++r) sm[r] += __shfl_xor(sm[r], off);
  }
  if (l31 == 0) {
    #pragma unroll
    for (int r = 0; r < 16; ++r) {
      int row = (r & 3) + 8 * (r >> 2) + 4 * hi;  // m74/m101 C/D row map
      size_t pi =
          (((size_t)task * BB + b) * NPTS + rowg * 32 + row) * 2 + half;
      pmx[pi] = fm[r];
      psm[pi] = sm[r];
    }
  }
}

// ---------------- merge halves + epilogue + next-round hq ----------------
__global__ __launch_bounds__(256) void merge_k(
    const float* __restrict__ pmx, const float* __restrict__ psm,
    MT m0, MT m1, MT m2, MT m3, float nel, float ie2n, int whq) {
  int task = blockIdx.z;
  MT M = (task == 0) ? m0 : (task == 1) ? m1 : (task == 2) ? m2 : m3;
  int idx = blockIdx.x * 256 + threadIdx.x;  // over BB*NPTS
  size_t pi = ((size_t)task * BB * NPTS + idx) * 2;
  float ma = pmx[pi], mb = pmx[pi + 1];
  float sa = psm[pi], sb = psm[pi + 1];
  float nm = fmaxf(ma, mb);
  float ss = sa * fexp2(ma - nm) + sb * fexp2(mb - nm);
  float f = nel * (__log2f(ss) + nm) + 0.5f * M.psq[idx];
  if (M.oldf) f = 0.5f * (M.oldf[idx] + f);
  M.out[idx] = f;
  if (whq) {
    float h = fmaf(f, ie2n, fmaf(M.lwn[idx], LOG2E, -0.5f * M.q2n[idx] * ie2n));
    M.hqn[idx] = h;
  }
}

// ---------------- loss epilogue (two-stage) ----------------
__global__ __launch_bounds__(256) void loss_part_k(
    const float* __restrict__ aW, const float* __restrict__ f_fin,
    const float* __restrict__ f_aa, const float* __restrict__ bW,
    const float* __restrict__ g_fin, const float* __restrict__ g_bb,
    float* __restrict__ part) {
  __shared__ float red[256];
  int i0 = blockIdx.x * 256 + threadIdx.x;
  float s = 0.f;
  for (int i = i0; i < BB * NPTS; i += 64 * 256)
    s += aW[i] * (f_fin[i] - f_aa[i]) + bW[i] * (g_fin[i] - g_bb[i]);
  red[threadIdx.x] = s;
  __syncthreads();
  for (int st = 128; st > 0; st >>= 1) {
    if (threadIdx.x < st) red[threadIdx.x] += red[threadIdx.x + st];
    __syncthreads();
  }
  if (threadIdx.x == 0) part[blockIdx.x] = red[0];
}

__global__ __launch_bounds__(64) void loss_fin_k(const float* __restrict__ part,
                                                 float* __restrict__ out) {
  float s = part[threadIdx.x];
  #pragma unroll
  for (int off = 32; off > 0; off >>= 1) s += __shfl_xor(s, off);
  if (threadIdx.x == 0) out[0] = s * (1.f / BB);
}

__global__ void write_val_k(float* out, float v) { out[0] = v; }

// ---------------- host ----------------

extern "C" void kernel_launch(void* const* d_in, const int* in_sizes, int n_in,
                              void* d_out, int out_size, void* d_ws,
                              size_t ws_size, hipStream_t stream) {
  (void)in_sizes; (void)n_in; (void)out_size;
  const float* X = (const float*)d_in[0];   // [B,N,D]
  const float* Y = (const float*)d_in[1];   // [B,M,D]
  const float* W1 = (const float*)d_in[2];  // [B,N]
  const float* W2 = (const float*)d_in[3];  // [B,M]
  float* out = (float*)d_out;

  char* base = (char*)d_ws;
  size_t off = 0;
  auto alloc_b = [&](size_t bytes) {
    void* r = base + off;
    off += (bytes + 255) & ~(size_t)255;
    return r;
  };
  const size_t nP = (size_t)BB * NPTS;
  _Float16* Xh = (_Float16*)alloc_b(nP * DIM * 2);
  _Float16* Yh = (_Float16*)alloc_b(nP * DIM * 2);
  float* x2 = (float*)alloc_b(nP * 4);
  float* y2 = (float*)alloc_b(nP * 4);
  float* aW = (float*)alloc_b(nP * 4);
  float* bW = (float*)alloc_b(nP * 4);
  float* la = (float*)alloc_b(nP * 4);
  float* lb = (float*)alloc_b(nP * 4);
  float* fba[2] = {(float*)alloc_b(nP * 4), (float*)alloc_b(nP * 4)};
  float* gab[2] = {(float*)alloc_b(nP * 4), (float*)alloc_b(nP * 4)};
  float* faa[2] = {(float*)alloc_b(nP * 4), (float*)alloc_b(nP * 4)};
  float* gbb[2] = {(float*)alloc_b(nP * 4), (float*)alloc_b(nP * 4)};
  float* hq = (float*)alloc_b(4 * nP * 4);
  float* pmx = (float*)alloc_b(4 * nP * 2 * 4);
  float* psm = (float*)alloc_b(4 * nP * 2 * 4);
  float* part = (float*)alloc_b(64 * 4);
  if (ws_size < off) {
    write_val_k<<<1, 1, 0, stream>>>(out, -(float)(ws_size >> 20));
    return;
  }

  // prep
  norm_weights_k<<<BB, 256, 0, stream>>>(W1, aW, la, NPTS);
  norm_weights_k<<<BB, 256, 0, stream>>>(W2, bW, lb, NPTS);
  sqnorm_cvt_k<<<BB * NPTS / 4, 256, 0, stream>>>(X, x2, Xh, BB * NPTS);
  sqnorm_cvt_k<<<BB * NPTS / 4, 256, 0, stream>>>(Y, y2, Yh, BB * NPTS);

  dim3 fg(128, BB, 4);        // (rowg*2+half, b, task)
  dim3 mg(BB * NPTS / 256, 1, 4);

  FT t0{Xh, Yh}, t1{Yh, Xh}, t2{Xh, Xh}, t3{Yh, Yh};
  float* hq0 = hq;                 // task0 slice (f_ba: pot=gab)
  float* hq1 = hq + 1 * nP;        // task1 (g_ab: pot=fba)
  float* hq2 = hq + 2 * nP;        // task2 (f_aa: pot=faa)
  float* hq3 = hq + 3 * nP;        // task3 (g_bb: pot=gbb)

  auto fused = [&](float eps) {
    fused_softmin_k<<<fg, 64, 0, stream>>>(t0, t1, t2, t3, hq, pmx, psm,
                                           LOG2E / eps);
  };
  // merge for all 4 tasks; out-task t feeds hq of consumer: t0->hq1, t1->hq0,
  // t2->hq2, t3->hq3 (lw/q2 of the consumer's Q side).
  auto merge = [&](float eps, float ie2n, int whq, const float* oF,
                   float* nF, const float* oG, float* nG, const float* oA,
                   float* nA, const float* oB, float* nB) {
    float nel = -eps * LN2;
    MT M0{x2, oF, nF, la, x2, hq1};
    MT M1{y2, oG, nG, lb, y2, hq0};
    MT M2{x2, oA, nA, la, x2, hq2};
    MT M3{y2, oB, nB, lb, y2, hq3};
    merge_k<<<mg, 256, 0, stream>>>(pmx, psm, M0, M1, M2, M3, nel, ie2n, whq);
  };

  // hq for the init round (no potential)
  init_hq_k<<<mg, 256, 0, stream>>>(la, lb, x2, y2, hq, LOG2E / EPS_H[0]);

  // init round at eps0 (no averaging); next round is loop it=0 at eps0
  fused(EPS_H[0]);
  merge(EPS_H[0], LOG2E / EPS_H[0], 1, nullptr, fba[0], nullptr, gab[0],
        nullptr, faa[0], nullptr, gbb[0]);

  // annealing loop: averaged updates, double-buffered
  int cur = 0;
  for (int it = 0; it < 9; ++it) {
    int nxt = cur ^ 1;
    float epsn = EPS_H[it < 8 ? it + 1 : 8];  // it=8 feeds final extrapolation
    fused(EPS_H[it]);
    merge(EPS_H[it], LOG2E / epsn, 1, fba[cur], fba[nxt], gab[cur], gab[nxt],
          faa[cur], faa[nxt], gbb[cur], gbb[nxt]);
    cur = nxt;
  }

  // final extrapolation at eps target (no averaging, no hq write)
  {
    int nxt = cur ^ 1;
    fused(EPS_H[8]);
    merge(EPS_H[8], 0.f, 0, nullptr, fba[nxt], nullptr, gab[nxt], nullptr,
          faa[nxt], nullptr, gbb[nxt]);
    loss_part_k<<<64, 256, 0, stream>>>(aW, fba[nxt], faa[nxt], bW, gab[nxt],
                                        gbb[nxt], part);
    loss_fin_k<<<1, 64, 0, stream>>>(part, out);
  }
}

// Round 10
// 466.681 us; speedup vs baseline: 1.2821x; 1.2821x over previous
//
#include <hip/hip_runtime.h>
#include <cstdint>
#include <cstddef>

// Problem constants (B,N,M,D fixed by the reference setup_inputs)
#define BB 8
#define NPTS 2048
#define DIM 64
#define CK 64            // Q cols staged per chunk
#define HALFC 1024       // cols per block (col-split by 2)
#define NC (HALFC / CK)  // 16 chunks
#define BROWS 64         // P rows per block (4 waves x 16 rows)

typedef _Float16 f16x8 __attribute__((ext_vector_type(8)));
typedef float f32x4 __attribute__((ext_vector_type(4)));

// eps schedule: DIAMETER^2 * 0.25^k down to blur^2 = 0.0025 (9 entries)
static const float EPS_H[9] = {100.0f, 25.0f, 6.25f, 1.5625f, 0.390625f,
                               0.09765625f, 0.0244140625f, 0.006103515625f,
                               0.0025f};
#define LOG2E 1.4426950408889634f
#define LN2 0.6931471805599453f

#if __has_builtin(__builtin_amdgcn_exp2f)
static __device__ __forceinline__ float fexp2(float x) {
  return __builtin_amdgcn_exp2f(x);
}
#else
static __device__ __forceinline__ float fexp2(float x) {
  float r;
  asm("v_exp_f32 %0, %1" : "=v"(r) : "v"(x));
  return r;
}
#endif

static __device__ __forceinline__ f32x4 vmax4(f32x4 a, f32x4 b) {
  f32x4 r;
  #pragma unroll
  for (int i = 0; i < 4; ++i) r[i] = fmaxf(a[i], b[i]);
  return r;
}

static __device__ __forceinline__ f32x4 vexp2_4(f32x4 a) {
  f32x4 r;
  #pragma unroll
  for (int i = 0; i < 4; ++i) r[i] = fexp2(a[i]);
  return r;
}

static __device__ __forceinline__ void gload_lds16(const void* g, void* l) {
  __builtin_amdgcn_global_load_lds(
      (const __attribute__((address_space(1))) void*)g,
      (__attribute__((address_space(3))) void*)l, 16, 0, 0);
}

struct FT {
  const _Float16* P;  // row-side points [B,2048,64]
  const _Float16* Q;  // reduce-side points [B,2048,64]
};
struct MT {
  const float* psq;  // |p|^2 on output rows
  const float* oldf; // averaging input (nullptr = none)
  float* out;        // potential output [B,2048]
  const float* lwn;  // log-weights for NEXT round's hq (Q-side of consumer)
  const float* q2n;  // |q|^2 for NEXT round's hq
  float* hqn;        // hq slice of the consumer task
};

// ---------------- prep kernels ----------------

__global__ __launch_bounds__(256) void norm_weights_k(
    const float* __restrict__ w, float* __restrict__ aout,
    float* __restrict__ logout, int n) {
  int b = blockIdx.x;
  const float* wb = w + (size_t)b * n;
  __shared__ float red[256];
  float s = 0.f;
  for (int i = threadIdx.x; i < n; i += 256) s += wb[i];
  red[threadIdx.x] = s;
  __syncthreads();
  for (int st = 128; st > 0; st >>= 1) {
    if (threadIdx.x < st) red[threadIdx.x] += red[threadIdx.x + st];
    __syncthreads();
  }
  float mass = red[0];
  if (mass == 0.f) mass = 1.f;
  float inv = 1.f / mass;
  for (int i = threadIdx.x; i < n; i += 256) {
    float av = wb[i] * inv;
    aout[(size_t)b * n + i] = av;
    logout[(size_t)b * n + i] = logf(av);
  }
}

// squared norm of each D=64 row + fp16 conversion: one wave per row
__global__ __launch_bounds__(256) void sqnorm_cvt_k(
    const float* __restrict__ X, float* __restrict__ sq,
    _Float16* __restrict__ Xh, int rows) {
  int row = blockIdx.x * 4 + (threadIdx.x >> 6);
  int lane = threadIdx.x & 63;
  if (row >= rows) return;
  float v = X[(size_t)row * DIM + lane];
  Xh[(size_t)row * DIM + lane] = (_Float16)v;
  float s = v * v;
  #pragma unroll
  for (int off = 32; off > 0; off >>= 1) s += __shfl_xor(s, off);
  if (lane == 0) sq[row] = s;
}

// hq init (no potential): hq[t][b][m] = lw*log2e - 0.5*q2*ie2
__global__ __launch_bounds__(256) void init_hq_k(
    const float* __restrict__ la, const float* __restrict__ lb,
    const float* __restrict__ x2, const float* __restrict__ y2,
    float* __restrict__ hq, float ie2) {
  int task = blockIdx.z;
  int idx = blockIdx.x * 256 + threadIdx.x;  // over BB*NPTS
  const float* lw = (task == 1 || task == 2) ? la : lb;
  const float* q2 = (task == 1 || task == 2) ? x2 : y2;
  hq[(size_t)task * BB * NPTS + idx] =
      fmaf(lw[idx], LOG2E, -0.5f * q2[idx] * ie2);
}

// ---------------- fused cost+softmin (col-split, max-occupancy) ----------
// Partial over one 1024-col half: (mx,sm) per row, with
//   v[r,m] = hq[m] + dot(P_r,Q_m)*ie2  (f16 MFMA 16x16x32, fp32 acc)
// Block = 4 waves x 16 P-rows; half's cols swept in 64-col LDS chunks,
// double-buffered via global_load_lds, counted vmcnt (never 0 in loop),
// raw s_barriers. hq staged once from precomputed global into 4KB LDS.
// LDS = 20KB -> 8 blocks/CU -> 32 waves/CU.
__global__ __launch_bounds__(256, 8) void fused_softmin_k(
    FT t0, FT t1, FT t2, FT t3, const float* __restrict__ hqG,
    float* __restrict__ pmx, float* __restrict__ psm, float ie2) {
  __shared__ float hql[HALFC];                       // 4 KB
  __shared__ __align__(16) _Float16 qb[2][CK * DIM]; // 2 x 8 KB
  FT T = (blockIdx.z == 0) ? t0
       : (blockIdx.z == 1) ? t1
       : (blockIdx.z == 2) ? t2 : t3;
  const int rowg = blockIdx.x >> 1, half = blockIdx.x & 1;
  const int b = blockIdx.y, task = blockIdx.z;
  const int tid = threadIdx.x;

  // stage hq slice for this col-half (precomputed on global)
  {
    const float* hqp = hqG + ((size_t)task * BB + b) * NPTS + half * HALFC;
    #pragma unroll
    for (int i = 0; i < HALFC / 256; ++i)
      hql[i * 256 + tid] = hqp[i * 256 + tid];
  }

  const int lane = tid & 63, wave = tid >> 6;
  const _Float16* Qb = T.Q + ((size_t)b * NPTS + half * HALFC) * DIM;

  // stage chunk -> qb[buf]: linear LDS dest, inverse-swizzled global source
  // (rule #21). granule gid holds Q[m0+gid/8][8 halfs of k-granule
  // (gid%8)^((gid/8)&7)]. 2 global_load_lds per wave per chunk.
  auto stage = [&](int buf, int chunk) {
    int m0 = chunk * CK;
    #pragma unroll
    for (int r = 0; r < 2; ++r) {
      int gbase = r * 256 + wave * 64;
      int gid = gbase + lane;
      int row = gid >> 3;
      int kg = (gid & 7) ^ (row & 7);
      const _Float16* src = Qb + (size_t)(m0 + row) * DIM + kg * 8;
      _Float16* dst = &qb[buf][(size_t)gbase * 8];  // wave-uniform base
      gload_lds16(src, dst);
    }
  };

  const int fr = lane & 15;        // MFMA row/col index within fragment
  const int g0 = lane >> 4;        // k-granule group (0..3)
  const int r0 = rowg * BROWS + wave * 16;
  const _Float16* Pb = T.P + ((size_t)b * NPTS + r0) * DIM;
  f16x8 a0 = *(const f16x8*)(Pb + fr * DIM + g0 * 8);
  f16x8 a1 = *(const f16x8*)(Pb + fr * DIM + g0 * 8 + 32);

  f32x4 mx4 = {-3.0e38f, -3.0e38f, -3.0e38f, -3.0e38f};
  f32x4 sm4 = {0.f, 0.f, 0.f, 0.f};

  auto compute = [&](int cur, int m0) {  // m0 local to the half
    const char* qbase = (const char*)&qb[cur][0];
    f32x4 v4[4];
    f32x4 cmx = mx4;
    #pragma unroll
    for (int s = 0; s < 4; ++s) {
      int row = s * 16 + fr;
      int byte0 = row * 128 + ((g0 ^ (row & 7)) << 4);
      int byte1 = row * 128 + (((g0 + 4) ^ (row & 7)) << 4);
      f16x8 b0 = *(const f16x8*)(qbase + byte0);
      f16x8 b1 = *(const f16x8*)(qbase + byte1);
      float hs = hql[m0 + s * 16 + fr];
      f32x4 z = {0.f, 0.f, 0.f, 0.f};
      f32x4 t = __builtin_amdgcn_mfma_f32_16x16x32_f16(a0, b0, z, 0, 0, 0);
      f32x4 acc = __builtin_amdgcn_mfma_f32_16x16x32_f16(a1, b1, t, 0, 0, 0);
      v4[s] = acc * ie2 + hs;
      cmx = vmax4(cmx, v4[s]);
    }
    f32x4 resc = vexp2_4(mx4 - cmx);
    f32x4 esum = vexp2_4(v4[0] - cmx) + vexp2_4(v4[1] - cmx);
    esum += vexp2_4(v4[2] - cmx) + vexp2_4(v4[3] - cmx);
    sm4 = sm4 * resc + esum;
    mx4 = cmx;
  };

  stage(0, 0);
  __syncthreads();  // one full drain: hql visible + chunk-0 staged

  for (int c = 0; c < NC - 1; ++c) {
    int cur = c & 1;
    stage(cur ^ 1, c + 1);  // buffer consumed in iter c-1 (B2 certified)
    // wait my chunk-c loads (2 oldest); keep chunk-(c+1)'s 2 in flight
    asm volatile("s_waitcnt vmcnt(2)" ::: "memory");
    __builtin_amdgcn_sched_barrier(0);
    __builtin_amdgcn_s_barrier();  // B1: chunk c globally staged
    __builtin_amdgcn_sched_barrier(0);
    compute(cur, c * CK);
    __builtin_amdgcn_sched_barrier(0);
    __builtin_amdgcn_s_barrier();  // B2: all waves done reading qb[cur]
    __builtin_amdgcn_sched_barrier(0);
  }
  // peeled last chunk: drain remaining loads (only time vmcnt hits 0)
  asm volatile("s_waitcnt vmcnt(0)" ::: "memory");
  __builtin_amdgcn_sched_barrier(0);
  __builtin_amdgcn_s_barrier();
  __builtin_amdgcn_sched_barrier(0);
  compute((NC - 1) & 1, (NC - 1) * CK);

  // reduce (mx,sm) over the 16 fr lanes (cols) of each row group
  #pragma unroll
  for (int off = 1; off < 16; off <<= 1) {
    #pragma unroll
    for (int q = 0; q < 4; ++q) {
      float omx = __shfl_xor(mx4[q], off);
      float osm = __shfl_xor(sm4[q], off);
      float nm = fmaxf(mx4[q], omx);
      sm4[q] = sm4[q] * fexp2(mx4[q] - nm) + osm * fexp2(omx - nm);
      mx4[q] = nm;
    }
  }
  if (fr == 0) {
    #pragma unroll
    for (int q = 0; q < 4; ++q) {
      int r = r0 + g0 * 4 + q;
      // layout [task][b][half][row] -> coalesced merge reads
      size_t pi = (((size_t)task * BB + b) * 2 + half) * NPTS + r;
      pmx[pi] = mx4[q];
      psm[pi] = sm4[q];
    }
  }
}

// ---------------- merge halves + epilogue + next-round hq ----------------
__global__ __launch_bounds__(256) void merge_k(
    const float* __restrict__ pmx, const float* __restrict__ psm,
    MT m0, MT m1, MT m2, MT m3, float nel, float ie2n, int whq) {
  int task = blockIdx.z;
  MT M = (task == 0) ? m0 : (task == 1) ? m1 : (task == 2) ? m2 : m3;
  int idx = blockIdx.x * 256 + threadIdx.x;  // over BB*NPTS
  int b = idx >> 11;                          // NPTS = 2048
  int r = idx & 2047;
  size_t pi = (((size_t)task * BB + b) * 2) * NPTS + r;
  float ma = pmx[pi], mb = pmx[pi + NPTS];
  float sa = psm[pi], sb = psm[pi + NPTS];
  float nm = fmaxf(ma, mb);
  float ss = sa * fexp2(ma - nm) + sb * fexp2(mb - nm);
  float f = nel * (__log2f(ss) + nm) + 0.5f * M.psq[idx];
  if (M.oldf) f = 0.5f * (M.oldf[idx] + f);
  M.out[idx] = f;
  if (whq) {
    float h = fmaf(f, ie2n, fmaf(M.lwn[idx], LOG2E, -0.5f * M.q2n[idx] * ie2n));
    M.hqn[idx] = h;
  }
}

// ---------------- loss epilogue (two-stage) ----------------
__global__ __launch_bounds__(256) void loss_part_k(
    const float* __restrict__ aW, const float* __restrict__ f_fin,
    const float* __restrict__ f_aa, const float* __restrict__ bW,
    const float* __restrict__ g_fin, const float* __restrict__ g_bb,
    float* __restrict__ part) {
  __shared__ float red[256];
  int i0 = blockIdx.x * 256 + threadIdx.x;
  float s = 0.f;
  for (int i = i0; i < BB * NPTS; i += 64 * 256)
    s += aW[i] * (f_fin[i] - f_aa[i]) + bW[i] * (g_fin[i] - g_bb[i]);
  red[threadIdx.x] = s;
  __syncthreads();
  for (int st = 128; st > 0; st >>= 1) {
    if (threadIdx.x < st) red[threadIdx.x] += red[threadIdx.x + st];
    __syncthreads();
  }
  if (threadIdx.x == 0) part[blockIdx.x] = red[0];
}

__global__ __launch_bounds__(64) void loss_fin_k(const float* __restrict__ part,
                                                 float* __restrict__ out) {
  float s = part[threadIdx.x];
  #pragma unroll
  for (int off = 32; off > 0; off >>= 1) s += __shfl_xor(s, off);
  if (threadIdx.x == 0) out[0] = s * (1.f / BB);
}

__global__ void write_val_k(float* out, float v) { out[0] = v; }

// ---------------- host ----------------

extern "C" void kernel_launch(void* const* d_in, const int* in_sizes, int n_in,
                              void* d_out, int out_size, void* d_ws,
                              size_t ws_size, hipStream_t stream) {
  (void)in_sizes; (void)n_in; (void)out_size;
  const float* X = (const float*)d_in[0];   // [B,N,D]
  const float* Y = (const float*)d_in[1];   // [B,M,D]
  const float* W1 = (const float*)d_in[2];  // [B,N]
  const float* W2 = (const float*)d_in[3];  // [B,M]
  float* out = (float*)d_out;

  char* base = (char*)d_ws;
  size_t off = 0;
  auto alloc_b = [&](size_t bytes) {
    void* r = base + off;
    off += (bytes + 255) & ~(size_t)255;
    return r;
  };
  const size_t nP = (size_t)BB * NPTS;
  _Float16* Xh = (_Float16*)alloc_b(nP * DIM * 2);
  _Float16* Yh = (_Float16*)alloc_b(nP * DIM * 2);
  float* x2 = (float*)alloc_b(nP * 4);
  float* y2 = (float*)alloc_b(nP * 4);
  float* aW = (float*)alloc_b(nP * 4);
  float* bW = (float*)alloc_b(nP * 4);
  float* la = (float*)alloc_b(nP * 4);
  float* lb = (float*)alloc_b(nP * 4);
  float* fba[2] = {(float*)alloc_b(nP * 4), (float*)alloc_b(nP * 4)};
  float* gab[2] = {(float*)alloc_b(nP * 4), (float*)alloc_b(nP * 4)};
  float* faa[2] = {(float*)alloc_b(nP * 4), (float*)alloc_b(nP * 4)};
  float* gbb[2] = {(float*)alloc_b(nP * 4), (float*)alloc_b(nP * 4)};
  float* hq = (float*)alloc_b(4 * nP * 4);
  float* pmx = (float*)alloc_b(4 * nP * 2 * 4);
  float* psm = (float*)alloc_b(4 * nP * 2 * 4);
  float* part = (float*)alloc_b(64 * 4);
  if (ws_size < off) {
    write_val_k<<<1, 1, 0, stream>>>(out, -(float)(ws_size >> 20));
    return;
  }

  // prep
  norm_weights_k<<<BB, 256, 0, stream>>>(W1, aW, la, NPTS);
  norm_weights_k<<<BB, 256, 0, stream>>>(W2, bW, lb, NPTS);
  sqnorm_cvt_k<<<BB * NPTS / 4, 256, 0, stream>>>(X, x2, Xh, BB * NPTS);
  sqnorm_cvt_k<<<BB * NPTS / 4, 256, 0, stream>>>(Y, y2, Yh, BB * NPTS);

  dim3 fg(64, BB, 4);        // (rowg*2+half, b, task)
  dim3 mg(BB * NPTS / 256, 1, 4);

  FT t0{Xh, Yh}, t1{Yh, Xh}, t2{Xh, Xh}, t3{Yh, Yh};
  float* hq0 = hq;                 // task0 slice (f_ba: pot=gab)
  float* hq1 = hq + 1 * nP;        // task1 (g_ab: pot=fba)
  float* hq2 = hq + 2 * nP;        // task2 (f_aa: pot=faa)
  float* hq3 = hq + 3 * nP;        // task3 (g_bb: pot=gbb)

  auto fused = [&](float eps) {
    fused_softmin_k<<<fg, 256, 0, stream>>>(t0, t1, t2, t3, hq, pmx, psm,
                                            LOG2E / eps);
  };
  // merge for all 4 tasks; out-task t feeds hq of consumer: t0->hq1, t1->hq0,
  // t2->hq2, t3->hq3 (lw/q2 of the consumer's Q side).
  auto merge = [&](float eps, float ie2n, int whq, const float* oF,
                   float* nF, const float* oG, float* nG, const float* oA,
                   float* nA, const float* oB, float* nB) {
    float nel = -eps * LN2;
    MT M0{x2, oF, nF, la, x2, hq1};
    MT M1{y2, oG, nG, lb, y2, hq0};
    MT M2{x2, oA, nA, la, x2, hq2};
    MT M3{y2, oB, nB, lb, y2, hq3};
    merge_k<<<mg, 256, 0, stream>>>(pmx, psm, M0, M1, M2, M3, nel, ie2n, whq);
  };

  // hq for the init round (no potential)
  init_hq_k<<<mg, 256, 0, stream>>>(la, lb, x2, y2, hq, LOG2E / EPS_H[0]);

  // init round at eps0 (no averaging); next round is loop it=0 at eps0
  fused(EPS_H[0]);
  merge(EPS_H[0], LOG2E / EPS_H[0], 1, nullptr, fba[0], nullptr, gab[0],
        nullptr, faa[0], nullptr, gbb[0]);

  // annealing loop: averaged updates, double-buffered
  int cur = 0;
  for (int it = 0; it < 9; ++it) {
    int nxt = cur ^ 1;
    float epsn = EPS_H[it < 8 ? it + 1 : 8];  // it=8 feeds final extrapolation
    fused(EPS_H[it]);
    merge(EPS_H[it], LOG2E / epsn, 1, fba[cur], fba[nxt], gab[cur], gab[nxt],
          faa[cur], faa[nxt], gbb[cur], gbb[nxt]);
    cur = nxt;
  }

  // final extrapolation at eps target (no averaging, no hq write)
  {
    int nxt = cur ^ 1;
    fused(EPS_H[8]);
    merge(EPS_H[8], 0.f, 0, nullptr, fba[nxt], nullptr, gab[nxt], nullptr,
          faa[nxt], nullptr, gbb[nxt]);
    loss_part_k<<<64, 256, 0, stream>>>(aW, fba[nxt], faa[nxt], bW, gab[nxt],
                                        gbb[nxt], part);
    loss_fin_k<<<1, 64, 0, stream>>>(part, out);
  }
}